// Round 8
// baseline (212.596 us; speedup 1.0000x reference)
//
#include <hip/hip_runtime.h>
#include <hip/hip_bf16.h>

// BERT-CRF NER forward loss, MI355X.
//
// Round-8 restructure driven by first real counters (r7: crf_chunk 75us,
// occupancy 19%, HBM 21%, VALU 21% -> latency/occupancy-bound):
//  k1 crf_feats: PURE streaming GEMM feats=hidden*W^T, exp -> E (global),
//     gold partials -> golds2. 256-thr blocks, wave = 16 K-slots x 4
//     row-slots x G=2 rows/lane; 12 independent f4 loads in flight/lane;
//     one sW ds_read feeds 2 rows (halves the invariant LDS tax).
//     1024 blocks -> 16 waves/CU (50% occupancy cap), VGPR<=128.
//  k2 crf_chain: per (chunk c, batch b) 1-wave block: 10x10 linear-domain
//     chunk product P_c = prod diag(E_t) T over 8 steps, T in 100 VGPRs,
//     pow-2 renorm with exact integer scale Cacc. 4096 blocks.
//  k3 crf_combine: per batch: stage 64 P-mats (25.6KB) to LDS, 63-matvec
//     chain with 2-deep reg pipeline, loss -> atomic mean into d_out.
//
// Linear-domain semantics: NEG_INF -> exact 0; renorm scale is power-of-2
// so bookkeeping is exact; growth <= 2^16/step, renorm every 4 steps.

#define NL 10
#define TL 512
#define HDIM 768
#define CS 8
#define NCHUNK 64
#define NB 64
#define LOG2E_F 1.4426950408889634f
#define LN2_F 0.6931471805599453f

// ---------------------------------------------------------------- k1
__global__ __launch_bounds__(256, 4) void crf_feats(
    const float* __restrict__ hidden, const float* __restrict__ W,
    const float* __restrict__ bias, const float* __restrict__ trans,
    const int* __restrict__ labels, float* __restrict__ E,
    float* __restrict__ golds2)
{
  const int tid = threadIdx.x;
  const int w = tid >> 6;        // wave 0..3
  const int lane = tid & 63;
  const int rs = lane >> 4;      // row-slot 0..3
  const int q = lane & 15;       // K-slot 0..15
  const int row0 = blockIdx.x * 32 + w * 8 + rs;  // G=0 row (global row id)
  const int row1 = row0 + 4;                       // G=1 row

  __shared__ float4 sW[1920];    // 30 KB: W as float4[l*192 + f4]
  __shared__ float sGold[4];

  for (int i = tid; i < 1920; i += 256)
    sW[i] = ((const float4*)W)[i];
  __syncthreads();

  float acc0[NL], acc1[NL];
#pragma unroll
  for (int l = 0; l < NL; ++l) { acc0[l] = 0.0f; acc1[l] = 0.0f; }

  const float4* __restrict__ h4 = (const float4*)hidden;
  const size_t b0 = (size_t)row0 * 192;
  const size_t b1 = (size_t)row1 * 192;

#pragma unroll
  for (int half = 0; half < 2; ++half) {
    // 12 independent coalesced loads (256B segments per row-slot group)
    float4 hA[6], hB[6];
#pragma unroll
    for (int j = 0; j < 6; ++j) {
      const int f4i = (half * 6 + j) * 16 + q;
      hA[j] = h4[b0 + f4i];
      hB[j] = h4[b1 + f4i];
    }
#pragma unroll
    for (int j = 0; j < 6; ++j) {
      const int f4i = (half * 6 + j) * 16 + q;
#pragma unroll
      for (int l = 0; l < NL; ++l) {
        const float4 wv = sW[l * 192 + f4i];  // one read feeds 2 rows
        acc0[l] += hA[j].x * wv.x + hA[j].y * wv.y + hA[j].z * wv.z + hA[j].w * wv.w;
        acc1[l] += hB[j].x * wv.x + hB[j].y * wv.y + hB[j].z * wv.z + hB[j].w * wv.w;
      }
    }
  }

  // reduce over the 16 K-slots (butterfly stays within 16-lane group)
#pragma unroll
  for (int l = 0; l < NL; ++l) {
#pragma unroll
    for (int off = 1; off < 16; off <<= 1) {
      acc0[l] += __shfl_xor(acc0[l], off);
      acc1[l] += __shfl_xor(acc1[l], off);
    }
    const float bl = bias[l];
    acc0[l] += bl; acc1[l] += bl;
  }

  // E write: lane (rs, q<10) stores element q of its 2 rows
  if (q < NL) {
    float s0 = acc0[0], s1 = acc1[0];
#pragma unroll
    for (int l = 1; l < NL; ++l) {
      s0 = (q == l) ? acc0[l] : s0;
      s1 = (q == l) ? acc1[l] : s1;
    }
    E[(size_t)row0 * NL + q] = exp2f(s0 * LOG2E_F);
    E[(size_t)row1 * NL + q] = exp2f(s1 * LOG2E_F);
  }

  // gold partials (owner lanes q==0; t=0 rows skipped)
  float g = 0.0f;
  if (q == 0) {
    if ((row0 & (TL - 1)) > 0) {
      const int cu = labels[row0], pv = labels[row0 - 1];
      float emit = acc0[0];
#pragma unroll
      for (int l = 1; l < NL; ++l) emit = (cu == l) ? acc0[l] : emit;
      g += emit + trans[cu * NL + pv];
    }
    {  // row1 = row0+4: t>=4 always valid
      const int cu = labels[row1], pv = labels[row1 - 1];
      float emit = acc1[0];
#pragma unroll
      for (int l = 1; l < NL; ++l) emit = (cu == l) ? acc1[l] : emit;
      g += emit + trans[cu * NL + pv];
    }
  }
  g += __shfl_xor(g, 16);
  g += __shfl_xor(g, 32);
  if (lane == 0) sGold[w] = g;
  __syncthreads();
  if (tid == 0)
    golds2[blockIdx.x] = sGold[0] + sGold[1] + sGold[2] + sGold[3];
}

// ---------------------------------------------------------------- k2
__global__ __launch_bounds__(64) void crf_chain(
    const float* __restrict__ E, const float* __restrict__ trans,
    float* __restrict__ Pmats, float* __restrict__ Cc)
{
  const int c = blockIdx.x;   // chunk 0..63
  const int b = blockIdx.y;   // batch
  const int lane = threadIdx.x;
  const int t0 = c * CS + 1;
  const int NT = (c == NCHUNK - 1) ? (CS - 1) : CS;  // 511 = 63*8 + 7

  __shared__ float sEl[CS * NL];  // up to 80 floats

  const float* __restrict__ src = E + (size_t)(b * TL + t0) * NL;
  const int n = NT * NL;
  for (int i = lane; i < n; i += 64) sEl[i] = src[i];
  __syncthreads();

  const int ep = lane % NL;  // column owned (lanes >=10 duplicate)

  float Tm[NL][NL];  // T = exp(transitions); NEG_INF -> exact 0
#pragma unroll
  for (int el = 0; el < NL; ++el)
#pragma unroll
    for (int k = 0; k < NL; ++k)
      Tm[el][k] = exp2f(trans[el * NL + k] * LOG2E_F);

  float p[NL];
#pragma unroll
  for (int el = 0; el < NL; ++el) p[el] = sEl[el] * Tm[el][ep];

  float Cacc = 0.0f;
  for (int s = 1; s < NT; ++s) {
    float pn[NL];
#pragma unroll
    for (int el = 0; el < NL; ++el) {
      float sum = Tm[el][0] * p[0];
#pragma unroll
      for (int k = 1; k < NL; ++k) sum += Tm[el][k] * p[k];
      pn[el] = sEl[s * NL + el] * sum;
    }
#pragma unroll
    for (int el = 0; el < NL; ++el) p[el] = pn[el];

    if ((s & 3) == 3 || s == NT - 1) {  // uniform renorm, exact pow-2
      float m = p[0];
#pragma unroll
      for (int el = 1; el < NL; ++el) m = fmaxf(m, p[el]);
#pragma unroll
      for (int off = 1; off < 64; off <<= 1) m = fmaxf(m, __shfl_xor(m, off));
      m = fmaxf(m, 1e-33f);
      const float e = floorf(log2f(m));
      const float scl = exp2f(-e);
      Cacc += e;
#pragma unroll
      for (int el = 0; el < NL; ++el) p[el] *= scl;
    }
  }

  float* __restrict__ Pb = Pmats + (size_t)(b * NCHUNK + c) * 100;
  if (lane < NL) {
#pragma unroll
    for (int el = 0; el < NL; ++el) Pb[el * NL + lane] = p[el];
  }
  if (lane == 0) Cc[b * NCHUNK + c] = Cacc;
}

// ---------------------------------------------------------------- k3
__global__ __launch_bounds__(64, 2) void crf_combine(
    const float* __restrict__ Pmats, const float* __restrict__ Cc,
    const float* __restrict__ golds2, float* __restrict__ out)
{
  const int b = blockIdx.x;
  const int lane = threadIdx.x;
  const int el = lane % NL;

  __shared__ float4 sP4[1600];  // 25.6 KB
  float* sP = (float*)sP4;

  const float4* __restrict__ src = (const float4*)(Pmats + (size_t)b * 6400);
#pragma unroll
  for (int i = 0; i < 25; ++i) sP4[i * 64 + lane] = src[i * 64 + lane];

  float cg = Cc[b * NCHUNK + lane];                       // 64 chunks
  float gg = (lane < 16) ? golds2[b * 16 + lane] : 0.0f;  // 16 block partials
#pragma unroll
  for (int off = 32; off; off >>= 1) {
    cg += __shfl_down(cg, off);
    gg += __shfl_down(gg, off);
  }
  float C = __shfl(cg, 0);
  const float gold = __shfl(gg, 0);

  __syncthreads();

  // v0 = e_START => v after chunk 0 = column START(=1) of P_0
  float v[NL];
#pragma unroll
  for (int p = 0; p < NL; ++p) v[p] = sP[p * NL + 1];

  float bufA[NL], bufB[NL];
#pragma unroll
  for (int k = 0; k < NL; ++k) bufA[k] = sP[1 * 100 + el * NL + k];

  for (int c = 1; c < NCHUNK; c += 2) {
    const int cn = (c + 1 < NCHUNK) ? (c + 1) : c;
#pragma unroll
    for (int k = 0; k < NL; ++k) bufB[k] = sP[cn * 100 + el * NL + k];

    float nv = bufA[0] * v[0];
#pragma unroll
    for (int k = 1; k < NL; ++k) nv += bufA[k] * v[k];
#pragma unroll
    for (int p = 0; p < NL; ++p) v[p] = __shfl(nv, p);

    if (c + 1 < NCHUNK) {
      const int cn2 = (c + 2 < NCHUNK) ? (c + 2) : (c + 1);
#pragma unroll
      for (int k = 0; k < NL; ++k) bufA[k] = sP[cn2 * 100 + el * NL + k];

      float nv2 = bufB[0] * v[0];
#pragma unroll
      for (int k = 1; k < NL; ++k) nv2 += bufB[k] * v[k];
#pragma unroll
      for (int p = 0; p < NL; ++p) v[p] = __shfl(nv2, p);

      float m = v[0];
#pragma unroll
      for (int p = 1; p < NL; ++p) m = fmaxf(m, v[p]);
      m = fmaxf(m, 1e-33f);
      const float e = floorf(log2f(m));
      const float scl = exp2f(-e);
      C += e;
#pragma unroll
      for (int p = 0; p < NL; ++p) v[p] *= scl;
    }
  }

  float s = 0.0f;
#pragma unroll
  for (int p = 0; p < NL; ++p) s += v[p];
  const float fwd = LN2_F * (log2f(s) + C);
  if (lane == 0) atomicAdd(out, (fwd - gold) * (1.0f / 64.0f));
}

extern "C" void kernel_launch(void* const* d_in, const int* in_sizes, int n_in,
                              void* d_out, int out_size, void* d_ws, size_t ws_size,
                              hipStream_t stream) {
  const float* hidden = (const float*)d_in[0];
  const float* W      = (const float*)d_in[1];
  const float* bias   = (const float*)d_in[2];
  const float* trans  = (const float*)d_in[3];
  const int*   labels = (const int*)d_in[4];

  float* ws     = (float*)d_ws;
  float* E      = ws;                       // 32768*10      = 327680
  float* Pmats  = E + 327680;               // 4096*100      = 409600
  float* Cc     = Pmats + 409600;           // 4096
  float* golds2 = Cc + 4096;                // 1024          (~2.97 MB total)

  hipMemsetAsync(d_out, 0, sizeof(float), stream);

  crf_feats<<<1024, 256, 0, stream>>>(hidden, W, bias, trans, labels, E, golds2);
  crf_chain<<<dim3(NCHUNK, NB), 64, 0, stream>>>(E, trans, Pmats, Cc);
  crf_combine<<<NB, 64, 0, stream>>>(Pmats, Cc, golds2, (float*)d_out);
}